// Round 1
// baseline (136.566 us; speedup 1.0000x reference)
//
#include <hip/hip_runtime.h>
#include <hip/hip_bf16.h>
#include <math.h>

// InfiniteContextAttention — exploit the reference's causal mask:
// only keys 0..15 (= compressed_k_in[:, :, :16]) are ever attended.
// Pipeline: q = hidden @ Wq^T  ->  16-key causal attention  ->  out = attn @ Wo^T
//
// Shapes: hidden [32][4096] (B*L=32 rows), Wq/Wo [4096][4096],
// compressed_k/v [2][32][2048][128] (only first 16 of the 2048 used).

#define HID 4096
#define NROW 32  // B*L = 2*16

// C[r][j] = sum_k A[r][k] * W[j][k]   (A: [32][4096], W: [4096][4096], C: [32][4096])
// grid 512 blocks, 256 thr (4 waves). Block owns 8 cols; wave owns 2 cols.
// Lane l owns K-slots {k0 + 4l .. +3} per 256-wide chunk; A chunk staged in LDS.
__global__ __launch_bounds__(256, 2)
void gemm32_kernel(const float* __restrict__ A,
                   const float* __restrict__ W,
                   float* __restrict__ C)
{
    __shared__ float As[NROW * 256];  // 32 KB
    const int tid  = threadIdx.x;
    const int lane = tid & 63;
    const int wave = tid >> 6;
    const int hi   = (lane >> 5) & 1;  // half-wave: 0 -> col jA, 1 -> col jB
    const int j0   = blockIdx.x * 8;
    const int jA   = j0 + wave * 2;
    const int jB   = jA + 1;

    float acc0[NROW], acc1[NROW];
#pragma unroll
    for (int r = 0; r < NROW; ++r) { acc0[r] = 0.f; acc1[r] = 0.f; }

    for (int k0 = 0; k0 < HID; k0 += 256) {
        __syncthreads();  // previous chunk's readers done
#pragma unroll
        for (int i = 0; i < 8; ++i) {
            int f = tid + 256 * i;     // flat float4 index, 0..2047
            int r = f >> 6;            // row
            int s = f & 63;            // float4 slot in chunk
            ((float4*)As)[f] = *(const float4*)(A + (size_t)r * HID + k0 + s * 4);
        }
        __syncthreads();
        float4 wA = *(const float4*)(W + (size_t)jA * HID + k0 + lane * 4);
        float4 wB = *(const float4*)(W + (size_t)jB * HID + k0 + lane * 4);
        const float4* As4 = (const float4*)As;
#pragma unroll
        for (int r = 0; r < NROW; ++r) {
            float4 a = As4[r * 64 + lane];  // lane-contiguous b128: conflict-free
            acc0[r] += a.x * wA.x + a.y * wA.y + a.z * wA.z + a.w * wA.w;
            acc1[r] += a.x * wB.x + a.y * wB.y + a.z * wB.z + a.w * wB.w;
        }
    }

    // Cross-lane reduction. Step 1 (mask 32): fold cols so lanes 0-31 carry jA,
    // lanes 32-63 carry jB. Then butterfly 16..1 completes the 32-lane sums.
    float v[NROW];
#pragma unroll
    for (int r = 0; r < NROW; ++r) {
        float send = hi ? acc0[r] : acc1[r];
        float recv = __shfl_xor(send, 32, 64);
        v[r] = (hi ? acc1[r] : acc0[r]) + recv;
    }
#pragma unroll
    for (int m = 16; m >= 1; m >>= 1) {
#pragma unroll
        for (int r = 0; r < NROW; ++r)
            v[r] += __shfl_xor(v[r], m, 64);
    }
    const int j = hi ? jB : jA;
#pragma unroll
    for (int r = 0; r < NROW; ++r)
        if ((lane & 31) == r)
            C[(size_t)r * HID + j] = v[r];
}

// One wave per (b, h, i): 16-key causal attention over compressed_k/v[:, :, :16].
// Lane l owns head-dims {2l, 2l+1}. In-place safe: each wave reads/writes only
// its own 128-dim slice, read-before-write within the same lane.
__global__ __launch_bounds__(256)
void attn16_kernel(const float* __restrict__ q,
                   const float* __restrict__ ck,
                   const float* __restrict__ cv,
                   float* __restrict__ o)
{
    const int lane = threadIdx.x & 63;
    const int g = blockIdx.x * 4 + (threadIdx.x >> 6);  // 0..1023
    const int b = g >> 9;
    const int h = (g >> 4) & 31;
    const int i = g & 15;

    const size_t qoff = ((size_t)(b * 16 + i)) * HID + h * 128 + 2 * lane;
    const float2 q2 = *(const float2*)(q + qoff);
    const size_t kvoff = ((size_t)(b * 32 + h)) * 2048 * 128 + 2 * lane;
    const float* kp = ck + kvoff;
    const float* vp = cv + kvoff;

    float e[16];
#pragma unroll
    for (int s = 0; s < 16; ++s) {
        float2 k2 = *(const float2*)(kp + (size_t)s * 128);
        float p = q2.x * k2.x + q2.y * k2.y;
#pragma unroll
        for (int m = 32; m >= 1; m >>= 1) p += __shfl_xor(p, m, 64);
        // i is wave-uniform: mask is branch-free and non-divergent
        e[s] = (s <= i) ? p * 0.08838834764831845f : -3.4e38f;
    }
    float mx = e[0];
#pragma unroll
    for (int s = 1; s < 16; ++s) mx = fmaxf(mx, e[s]);
    float den = 0.f;
#pragma unroll
    for (int s = 0; s < 16; ++s) { e[s] = __expf(e[s] - mx); den += e[s]; }
    const float inv = 1.0f / den;

    float ox = 0.f, oy = 0.f;
#pragma unroll
    for (int s = 0; s < 16; ++s) {
        float2 v2 = *(const float2*)(vp + (size_t)s * 128);
        ox += e[s] * v2.x;
        oy += e[s] * v2.y;
    }
    float2 res;
    res.x = ox * inv;
    res.y = oy * inv;
    *(float2*)(o + qoff) = res;
}

extern "C" void kernel_launch(void* const* d_in, const int* in_sizes, int n_in,
                              void* d_out, int out_size, void* d_ws, size_t ws_size,
                              hipStream_t stream) {
    const float* hidden = (const float*)d_in[0];  // [2][16][4096]
    const float* ck     = (const float*)d_in[3];  // [2][32][2048][128]
    const float* cv     = (const float*)d_in[4];
    const float* Wq     = (const float*)d_in[5];  // [4096][4096]
    const float* Wo     = (const float*)d_in[8];
    float* out = (float*)d_out;                   // [2][16][4096]
    float* q   = (float*)d_ws;                    // 512 KB scratch: q / attn (in-place)

    hipLaunchKernelGGL(gemm32_kernel, dim3(512), dim3(256), 0, stream, hidden, Wq, q);
    hipLaunchKernelGGL(attn16_kernel, dim3(256), dim3(256), 0, stream, q, ck, cv, q);
    hipLaunchKernelGGL(gemm32_kernel, dim3(512), dim3(256), 0, stream, q, Wo, out);
}